// Round 13
// baseline (68.009 us; speedup 1.0000x reference)
//
#include <hip/hip_runtime.h>
#include <stdint.h>
#include <math.h>

#define BB 4
#define LL 12
#define NN 512
#define DMM 64
#define HH 8
#define DD 8
#define SK 35
#define IDX_TOTAL (NN*SK)   // 17920
#define PADK 12             // 48B row pitch: b128-aligned, 2-way-free bank walk

// ---------------------------------------------------------------------------
// Threefry-2x32 (JAX-exact: 20 rounds, rotations {13,15,26,6}/{17,29,16,24})
// ---------------------------------------------------------------------------
__device__ __forceinline__ void tf2x32(uint32_t k0, uint32_t k1, uint32_t x0, uint32_t x1,
                                       uint32_t& o0, uint32_t& o1) {
  const uint32_t ks2 = k0 ^ k1 ^ 0x1BD11BDAu;
  uint32_t a = x0 + k0, b = x1 + k1;
#define TF_R(r) { a += b; b = (b << (r)) | (b >> (32 - (r))); b ^= a; }
  TF_R(13) TF_R(15) TF_R(26) TF_R(6)
  a += k1;  b += ks2 + 1u;
  TF_R(17) TF_R(29) TF_R(16) TF_R(24)
  a += ks2; b += k0 + 2u;
  TF_R(13) TF_R(15) TF_R(26) TF_R(6)
  a += k0;  b += k1 + 3u;
  TF_R(17) TF_R(29) TF_R(16) TF_R(24)
  a += k1;  b += ks2 + 4u;
  TF_R(13) TF_R(15) TF_R(26) TF_R(6)
  a += ks2; b += k0 + 5u;
#undef TF_R
  o0 = a; o1 = b;
}

// ---------------------------------------------------------------------------
// K1: fused projections (y=0,1,2; 64-row tiles) + idx generation (y=3).
// ---------------------------------------------------------------------------
__global__ __launch_bounds__(256) void proj_idx_kernel(
    const float* __restrict__ Xq, const float* __restrict__ Xk, const float* __restrict__ Xv,
    const float* __restrict__ Wq_, const float* __restrict__ Wk_, const float* __restrict__ Wv_,
    const float* __restrict__ bq_, const float* __restrict__ bk_, const float* __restrict__ bv_,
    float* __restrict__ Oq, float* __restrict__ Ok, float* __restrict__ Ov,
    int* __restrict__ idxT) {
  const int tz = blockIdx.y;
  if (tz == 3) {
    int gid = blockIdx.x * 256 + threadIdx.x;
    if (gid < IDX_TOTAL) {
      int r = gid & (NN - 1);     // idxT flat = s*512 + r
      int s = gid >> 9;
      uint32_t ka, kb;
      tf2x32(0u, 42u, 0u, 1u, ka, kb);
      uint32_t b1, b2;
      tf2x32(ka, kb, 0u, (uint32_t)(r * SK + s), b1, b2);   // counter = row-major (r,s)
      idxT[gid] = (int)((b1 ^ b2) & (uint32_t)(NN - 1));
    }
    return;
  }
  const float* X    = (tz == 0) ? Xq  : (tz == 1) ? Xk  : Xv;
  const float* W    = (tz == 0) ? Wq_ : (tz == 1) ? Wk_ : Wv_;
  const float* bias = (tz == 0) ? bq_ : (tz == 1) ? bk_ : bv_;
  float* O          = (tz == 0) ? Oq  : (tz == 1) ? Ok  : Ov;

  __shared__ __align__(16) float Ws[64][64];
  __shared__ __align__(16) float Xs[64][68];
  __shared__ float bs[64];

  const int tid = threadIdx.x;
  const size_t rowBase = (size_t)blockIdx.x * 64;
  const float* Xb = X + rowBase * 64;
  #pragma unroll
  for (int i = 0; i < 4; ++i) {
    int idx = tid + i*256;
    ((float4*)Ws)[idx] = ((const float4*)W)[idx];
    int r = idx >> 4, c = (idx & 15) << 2;
    *(float4*)&Xs[r][c] = ((const float4*)Xb)[idx];
  }
  if (tid < 64) bs[tid] = bias[tid];
  __syncthreads();

  const int hcol = tid & 7;   // head (8 cols)
  const int rb   = tid >> 3;  // 0..31; rows rb, rb+32
  float4 bv0 = *(float4*)&bs[hcol*8];
  float4 bv1 = *(float4*)&bs[hcol*8+4];
  float acc[2][8];
  #pragma unroll
  for (int i = 0; i < 2; ++i) {
    acc[i][0]=bv0.x; acc[i][1]=bv0.y; acc[i][2]=bv0.z; acc[i][3]=bv0.w;
    acc[i][4]=bv1.x; acc[i][5]=bv1.y; acc[i][6]=bv1.z; acc[i][7]=bv1.w;
  }
  #pragma unroll 8
  for (int m = 0; m < 64; ++m) {
    float4 w0 = *(const float4*)&Ws[m][hcol*8];
    float4 w1 = *(const float4*)&Ws[m][hcol*8+4];
    float x0 = Xs[rb][m];
    float x1 = Xs[rb+32][m];
    acc[0][0]=fmaf(x0,w0.x,acc[0][0]); acc[0][1]=fmaf(x0,w0.y,acc[0][1]);
    acc[0][2]=fmaf(x0,w0.z,acc[0][2]); acc[0][3]=fmaf(x0,w0.w,acc[0][3]);
    acc[0][4]=fmaf(x0,w1.x,acc[0][4]); acc[0][5]=fmaf(x0,w1.y,acc[0][5]);
    acc[0][6]=fmaf(x0,w1.z,acc[0][6]); acc[0][7]=fmaf(x0,w1.w,acc[0][7]);
    acc[1][0]=fmaf(x1,w0.x,acc[1][0]); acc[1][1]=fmaf(x1,w0.y,acc[1][1]);
    acc[1][2]=fmaf(x1,w0.z,acc[1][2]); acc[1][3]=fmaf(x1,w0.w,acc[1][3]);
    acc[1][4]=fmaf(x1,w1.x,acc[1][4]); acc[1][5]=fmaf(x1,w1.y,acc[1][5]);
    acc[1][6]=fmaf(x1,w1.z,acc[1][6]); acc[1][7]=fmaf(x1,w1.w,acc[1][7]);
  }
  #pragma unroll
  for (int i = 0; i < 2; ++i) {
    size_t R = rowBase + rb + 32*i;
    int bI = (int)(R / (LL*NN));
    int lI = (int)((R / NN) % LL);
    int nI = (int)(R % NN);
    size_t off = ((((size_t)bI*HH + hcol)*LL + lI)*NN + nI)*DD;
    *(float4*)&O[off]     = make_float4(acc[i][0],acc[i][1],acc[i][2],acc[i][3]);
    *(float4*)&O[off + 4] = make_float4(acc[i][4],acc[i][5],acc[i][6],acc[i][7]);
  }
}

// ---------------------------------------------------------------------------
// K2: single back-end kernel. 768 blocks (= (b,h,l) x half, 3/CU balanced)
// x 256 threads. Each block: stage K (full slab) -> M for full slab
// (2 rows/thread, duplicated across sibling halves) -> rank own half
// (1 row/thread, u64 scan) -> compact winners + capture q from regs ->
// vmean(wave0) + attention (4 waves pair-sweep; K from LDS, V from L2)
// -> output own 256 rows.
// ---------------------------------------------------------------------------
__global__ __launch_bounds__(256) void back_kernel(
    const float* __restrict__ Qt, const float* __restrict__ Kt,
    const float* __restrict__ Vt, const int* __restrict__ idxT,
    float* __restrict__ out) {
  const int gb = blockIdx.x;
  const int bid = gb >> 1, half = gb & 1;
  const int l = bid % LL;
  const int h = (bid / LL) % HH;
  const int b = bid / (LL*HH);
  const int tid = threadIdx.x;
  const int wave = tid >> 6, lane = tid & 63;

  __shared__ __align__(16) float Ks[NN][PADK];        // 24KB
  __shared__ __align__(16) uint64_t keys[NN];         // 4KB
  __shared__ int sel[256];                            // 1KB
  __shared__ int listRow[SK];
  __shared__ int listSlot[SK];
  __shared__ int cnt2;
  __shared__ __align__(16) float Qw[SK][8];           // winner q rows
  __shared__ __align__(16) float attnOut[SK][8];
  __shared__ __align__(16) float redD[4][64][8];      // 8KB
  __shared__ __align__(16) float vm[8];

  const size_t slabOff = (size_t)bid * (NN*DD);

  // ---- stage K (full slab), load q rows tid & tid+256, prefetch idx row tid ----
  {
    const float4* kg = (const float4*)(Kt + slabOff);
    float4 a0 = kg[tid*2], a1 = kg[tid*2+1];
    float4 b0 = kg[(tid+256)*2], b1 = kg[(tid+256)*2+1];
    *(float4*)&Ks[tid][0] = a0;     *(float4*)&Ks[tid][4] = a1;
    *(float4*)&Ks[tid+256][0] = b0; *(float4*)&Ks[tid+256][4] = b1;
  }
  const float4* qg = (const float4*)(Qt + slabOff);
  float4 q0a = qg[tid*2],       q0b = qg[tid*2+1];        // row tid
  float4 q1a = qg[(tid+256)*2], q1b = qg[(tid+256)*2+1];  // row tid+256
  int jv1[SK];
  {
    const int* gi = idxT + tid;
    #pragma unroll
    for (int s = 0; s < SK; ++s) jv1[s] = gi[s*NN];   // coalesced, pre-barrier
  }
  sel[tid] = -1;
  if (tid == 0) cnt2 = 0;
  __syncthreads();

  // ---- M for row tid+256: issue idx loads first (hide under M1 compute) ----
  int jv2[SK];
  {
    const int* gi = idxT + tid + 256;
    #pragma unroll
    for (int s = 0; s < SK; ++s) jv2[s] = gi[s*NN];
  }
  // ---- M for row tid -> key ----
  {
    float mx = -INFINITY, sm = 0.f;
    #pragma unroll
    for (int s = 0; s < SK; ++s) {
      int j = jv1[s];
      float4 c0 = *(const float4*)&Ks[j][0];
      float4 c1 = *(const float4*)&Ks[j][4];
      float dot = q0a.x*c0.x + q0a.y*c0.y + q0a.z*c0.z + q0a.w*c0.w
                + q0b.x*c1.x + q0b.y*c1.y + q0b.z*c1.z + q0b.w*c1.w;
      mx = fmaxf(mx, dot);
      sm += dot;
    }
    float m = mx - sm * (1.0f/NN);
    uint32_t u = __float_as_uint(m);
    uint32_t fk = (u & 0x80000000u) ? ~u : (u | 0x80000000u);
    keys[tid] = ((uint64_t)fk << 32) | (uint32_t)(NN - 1 - tid);
  }
  // ---- M for row tid+256 -> key ----
  {
    float mx = -INFINITY, sm = 0.f;
    #pragma unroll
    for (int s = 0; s < SK; ++s) {
      int j = jv2[s];
      float4 c0 = *(const float4*)&Ks[j][0];
      float4 c1 = *(const float4*)&Ks[j][4];
      float dot = q1a.x*c0.x + q1a.y*c0.y + q1a.z*c0.z + q1a.w*c0.w
                + q1b.x*c1.x + q1b.y*c1.y + q1b.z*c1.z + q1b.w*c1.w;
      mx = fmaxf(mx, dot);
      sm += dot;
    }
    float m = mx - sm * (1.0f/NN);
    uint32_t u = __float_as_uint(m);
    uint32_t fk = (u & 0x80000000u) ? ~u : (u | 0x80000000u);
    keys[tid + 256] = ((uint64_t)fk << 32) | (uint32_t)(NN - 1 - (tid + 256));
  }
  __syncthreads();

  // ---- rank own-half row; compact winners; capture q from own regs ----
  {
    const int row = half*256 + tid;
    const uint64_t my = keys[row];
    const ulonglong2* kq = (const ulonglong2*)keys;
    int cnt = 0;
    #pragma unroll 8
    for (int jb = 0; jb < NN/2; ++jb) {
      ulonglong2 kv = kq[jb];            // uniform broadcast read
      cnt += (kv.x > my) ? 1 : 0;
      cnt += (kv.y > my) ? 1 : 0;
    }
    if (cnt < SK) {
      sel[tid] = cnt;
      int p = atomicAdd(&cnt2, 1);
      listRow[p] = row;
      listSlot[p] = cnt;
      // thread tid computed M (and holds q) for rows tid and tid+256;
      // its own-half row is tid (half=0) or tid+256 (half=1).
      float4 mqa = half ? q1a : q0a;
      float4 mqb = half ? q1b : q0b;
      *(float4*)&Qw[p][0] = mqa;
      *(float4*)&Qw[p][4] = mqb;
    }
  }
  __syncthreads();
  const int C = cnt2;

  const float4* vp = (const float4*)(Vt + slabOff);

  // ---- wave0: vmean from global V (L2-resident, coalesced) ----
  if (wave == 0) {
    float a[8] = {0,0,0,0,0,0,0,0};
    #pragma unroll
    for (int j = 0; j < 8; ++j) {
      const float4* vr = vp + (size_t)(lane + 64*j)*2;
      float4 v0 = vr[0], v1 = vr[1];
      a[0]+=v0.x; a[1]+=v0.y; a[2]+=v0.z; a[3]+=v0.w;
      a[4]+=v1.x; a[5]+=v1.y; a[6]+=v1.z; a[7]+=v1.w;
    }
    *(float4*)&redD[0][lane][0] = make_float4(a[0],a[1],a[2],a[3]);
    *(float4*)&redD[0][lane][4] = make_float4(a[4],a[5],a[6],a[7]);
    const int d = lane & 7, g = lane >> 3;
    float s = 0.f;
    #pragma unroll
    for (int k = 0; k < 8; ++k) s += redD[0][g*8+k][d];
    s += __shfl_xor(s, 8); s += __shfl_xor(s, 16); s += __shfl_xor(s, 32);
    if (lane < 8) vm[lane] = s * (1.0f/NN);
  }

  // ---- attention: 4 waves pair-sweep C winners; K from LDS, V from L2 ----
  auto do_rows = [&](int t1, int t2, bool has2) {
    const int s1o = listSlot[t1];
    const int s2o = has2 ? listSlot[t2] : s1o;
    float4 q1aa = *(const float4*)&Qw[t1][0];       // broadcast LDS reads
    float4 q1bb = *(const float4*)&Qw[t1][4];
    float4 q2aa = has2 ? *(const float4*)&Qw[t2][0] : q1aa;
    float4 q2bb = has2 ? *(const float4*)&Qw[t2][4] : q1bb;
    float p1[8], p2[8];
    float mx1 = -INFINITY, mx2 = -INFINITY;
    #pragma unroll
    for (int j = 0; j < 8; ++j) {
      int key = lane + 64*j;
      float4 ca = *(const float4*)&Ks[key][0];
      float4 cb = *(const float4*)&Ks[key][4];
      float s1 = q1aa.x*ca.x + q1aa.y*ca.y + q1aa.z*ca.z + q1aa.w*ca.w
               + q1bb.x*cb.x + q1bb.y*cb.y + q1bb.z*cb.z + q1bb.w*cb.w;
      float s2 = q2aa.x*ca.x + q2aa.y*ca.y + q2aa.z*ca.z + q2aa.w*ca.w
               + q2bb.x*cb.x + q2bb.y*cb.y + q2bb.z*cb.z + q2bb.w*cb.w;
      s1 *= 0.35355339059327373f;          // 1/sqrt(8)
      s2 *= 0.35355339059327373f;
      p1[j] = s1; p2[j] = s2;
      mx1 = fmaxf(mx1, s1); mx2 = fmaxf(mx2, s2);
    }
    #pragma unroll
    for (int off = 32; off >= 1; off >>= 1) {
      mx1 = fmaxf(mx1, __shfl_xor(mx1, off));
      mx2 = fmaxf(mx2, __shfl_xor(mx2, off));
    }
    float sum1 = 0.f, sum2 = 0.f;
    #pragma unroll
    for (int j = 0; j < 8; ++j) {
      p1[j] = __expf(p1[j] - mx1); sum1 += p1[j];
      p2[j] = __expf(p2[j] - mx2); sum2 += p2[j];
    }
    #pragma unroll
    for (int off = 32; off >= 1; off >>= 1) {
      sum1 += __shfl_xor(sum1, off);
      sum2 += __shfl_xor(sum2, off);
    }
    float a1[8] = {0,0,0,0,0,0,0,0}, a2[8] = {0,0,0,0,0,0,0,0};
    #pragma unroll
    for (int j = 0; j < 8; ++j) {
      int key = lane + 64*j;
      float4 va = vp[key*2], vb = vp[key*2+1];
      float w1 = p1[j], w2 = p2[j];
      a1[0]=fmaf(w1,va.x,a1[0]); a1[1]=fmaf(w1,va.y,a1[1]);
      a1[2]=fmaf(w1,va.z,a1[2]); a1[3]=fmaf(w1,va.w,a1[3]);
      a1[4]=fmaf(w1,vb.x,a1[4]); a1[5]=fmaf(w1,vb.y,a1[5]);
      a1[6]=fmaf(w1,vb.z,a1[6]); a1[7]=fmaf(w1,vb.w,a1[7]);
      a2[0]=fmaf(w2,va.x,a2[0]); a2[1]=fmaf(w2,va.y,a2[1]);
      a2[2]=fmaf(w2,va.z,a2[2]); a2[3]=fmaf(w2,va.w,a2[3]);
      a2[4]=fmaf(w2,vb.x,a2[4]); a2[5]=fmaf(w2,vb.y,a2[5]);
      a2[6]=fmaf(w2,vb.z,a2[6]); a2[7]=fmaf(w2,vb.w,a2[7]);
    }
    const int d = lane & 7, g = lane >> 3;
    {
      *(float4*)&redD[wave][lane][0] = make_float4(a1[0],a1[1],a1[2],a1[3]);
      *(float4*)&redD[wave][lane][4] = make_float4(a1[4],a1[5],a1[6],a1[7]);
      float s = 0.f;
      #pragma unroll
      for (int k = 0; k < 8; ++k) s += redD[wave][g*8+k][d];
      s += __shfl_xor(s, 8); s += __shfl_xor(s, 16); s += __shfl_xor(s, 32);
      if (lane < 8) attnOut[s1o][lane] = s * (1.0f / sum1);
    }
    if (has2) {
      *(float4*)&redD[wave][lane][0] = make_float4(a2[0],a2[1],a2[2],a2[3]);
      *(float4*)&redD[wave][lane][4] = make_float4(a2[4],a2[5],a2[6],a2[7]);
      float s = 0.f;
      #pragma unroll
      for (int k = 0; k < 8; ++k) s += redD[wave][g*8+k][d];
      s += __shfl_xor(s, 8); s += __shfl_xor(s, 16); s += __shfl_xor(s, 32);
      if (lane < 8) attnOut[s2o][lane] = s * (1.0f / sum2);
    }
  };
  for (int it = wave*2; it < C; it += 8)
    do_rows(it, it + 1, (it + 1) < C);
  __syncthreads();

  // ---- output: local row tid -> global row half*256+tid ----
  {
    int t = sel[tid];
    float4 o0, o1;
    if (t >= 0) { o0 = *(const float4*)&attnOut[t][0]; o1 = *(const float4*)&attnOut[t][4]; }
    else        { o0 = *(const float4*)&vm[0];         o1 = *(const float4*)&vm[4]; }
    const int n = half*256 + tid;
    float* ob = out + ((size_t)(b*LL + l)*NN + n)*DMM + h*DD;
    *(float4*)&ob[0] = o0;
    *(float4*)&ob[4] = o1;
  }
}

// ---------------------------------------------------------------------------
extern "C" void kernel_launch(void* const* d_in, const int* in_sizes, int n_in,
                              void* d_out, int out_size, void* d_ws, size_t ws_size,
                              hipStream_t stream) {
  const float* q  = (const float*)d_in[0];
  const float* k  = (const float*)d_in[1];
  const float* v  = (const float*)d_in[2];
  const float* Wq = (const float*)d_in[3];
  const float* bq = (const float*)d_in[4];
  const float* Wk = (const float*)d_in[5];
  const float* bk = (const float*)d_in[6];
  const float* Wv = (const float*)d_in[7];
  const float* bv = (const float*)d_in[8];
  float* out = (float*)d_out;

  const size_t slab = (size_t)BB*HH*LL*NN*DD;      // 1,572,864 floats
  float* qT = (float*)d_ws;
  float* kT = qT + slab;
  float* vT = kT + slab;
  int*   idxT = (int*)(vT + slab);                 // 17920 ints

  proj_idx_kernel<<<dim3((BB*LL*NN)/64, 4), 256, 0, stream>>>(
      q, k, v, Wq, Wk, Wv, bq, bk, bv, qT, kT, vT, idxT);
  back_kernel<<<BB*HH*LL*2, 256, 0, stream>>>(qT, kT, vT, idxT, out);
}

// Round 16
// 57.151 us; speedup vs baseline: 1.1900x; 1.1900x over previous
//
#include <hip/hip_runtime.h>
#include <stdint.h>
#include <math.h>

#define BB 4
#define LL 12
#define NN 512
#define DMM 64
#define HH 8
#define DD 8
#define SK 35
#define IDX_TOTAL (NN*SK)   // 17920
#define PADK 12             // 48B row pitch: b128-aligned, 8-bank rotation

// ---------------------------------------------------------------------------
// Threefry-2x32 (JAX-exact: 20 rounds, rotations {13,15,26,6}/{17,29,16,24})
// ---------------------------------------------------------------------------
__device__ __forceinline__ void tf2x32(uint32_t k0, uint32_t k1, uint32_t x0, uint32_t x1,
                                       uint32_t& o0, uint32_t& o1) {
  const uint32_t ks2 = k0 ^ k1 ^ 0x1BD11BDAu;
  uint32_t a = x0 + k0, b = x1 + k1;
#define TF_R(r) { a += b; b = (b << (r)) | (b >> (32 - (r))); b ^= a; }
  TF_R(13) TF_R(15) TF_R(26) TF_R(6)
  a += k1;  b += ks2 + 1u;
  TF_R(17) TF_R(29) TF_R(16) TF_R(24)
  a += ks2; b += k0 + 2u;
  TF_R(13) TF_R(15) TF_R(26) TF_R(6)
  a += k0;  b += k1 + 3u;
  TF_R(17) TF_R(29) TF_R(16) TF_R(24)
  a += k1;  b += ks2 + 4u;
  TF_R(13) TF_R(15) TF_R(26) TF_R(6)
  a += ks2; b += k0 + 5u;
#undef TF_R
  o0 = a; o1 = b;
}

// ---------------------------------------------------------------------------
// K1: fused projections (y=0,1,2; 64-row tiles) + idx generation (y=3).
// ---------------------------------------------------------------------------
__global__ __launch_bounds__(256) void proj_idx_kernel(
    const float* __restrict__ Xq, const float* __restrict__ Xk, const float* __restrict__ Xv,
    const float* __restrict__ Wq_, const float* __restrict__ Wk_, const float* __restrict__ Wv_,
    const float* __restrict__ bq_, const float* __restrict__ bk_, const float* __restrict__ bv_,
    float* __restrict__ Oq, float* __restrict__ Ok, float* __restrict__ Ov,
    int* __restrict__ idxT) {
  const int tz = blockIdx.y;
  if (tz == 3) {
    int gid = blockIdx.x * 256 + threadIdx.x;
    if (gid < IDX_TOTAL) {
      int r = gid & (NN - 1);     // idxT flat = s*512 + r
      int s = gid >> 9;
      uint32_t ka, kb;
      tf2x32(0u, 42u, 0u, 1u, ka, kb);
      uint32_t b1, b2;
      tf2x32(ka, kb, 0u, (uint32_t)(r * SK + s), b1, b2);   // counter = row-major (r,s)
      idxT[gid] = (int)((b1 ^ b2) & (uint32_t)(NN - 1));
    }
    return;
  }
  const float* X    = (tz == 0) ? Xq  : (tz == 1) ? Xk  : Xv;
  const float* W    = (tz == 0) ? Wq_ : (tz == 1) ? Wk_ : Wv_;
  const float* bias = (tz == 0) ? bq_ : (tz == 1) ? bk_ : bv_;
  float* O          = (tz == 0) ? Oq  : (tz == 1) ? Ok  : Ov;

  __shared__ __align__(16) float Ws[64][64];
  __shared__ __align__(16) float Xs[64][68];
  __shared__ float bs[64];

  const int tid = threadIdx.x;
  const size_t rowBase = (size_t)blockIdx.x * 64;
  const float* Xb = X + rowBase * 64;
  #pragma unroll
  for (int i = 0; i < 4; ++i) {
    int idx = tid + i*256;
    ((float4*)Ws)[idx] = ((const float4*)W)[idx];
    int r = idx >> 4, c = (idx & 15) << 2;
    *(float4*)&Xs[r][c] = ((const float4*)Xb)[idx];
  }
  if (tid < 64) bs[tid] = bias[tid];
  __syncthreads();

  const int hcol = tid & 7;   // head (8 cols)
  const int rb   = tid >> 3;  // 0..31; rows rb, rb+32
  float4 bv0 = *(float4*)&bs[hcol*8];
  float4 bv1 = *(float4*)&bs[hcol*8+4];
  float acc[2][8];
  #pragma unroll
  for (int i = 0; i < 2; ++i) {
    acc[i][0]=bv0.x; acc[i][1]=bv0.y; acc[i][2]=bv0.z; acc[i][3]=bv0.w;
    acc[i][4]=bv1.x; acc[i][5]=bv1.y; acc[i][6]=bv1.z; acc[i][7]=bv1.w;
  }
  #pragma unroll 8
  for (int m = 0; m < 64; ++m) {
    float4 w0 = *(const float4*)&Ws[m][hcol*8];
    float4 w1 = *(const float4*)&Ws[m][hcol*8+4];
    float x0 = Xs[rb][m];
    float x1 = Xs[rb+32][m];
    acc[0][0]=fmaf(x0,w0.x,acc[0][0]); acc[0][1]=fmaf(x0,w0.y,acc[0][1]);
    acc[0][2]=fmaf(x0,w0.z,acc[0][2]); acc[0][3]=fmaf(x0,w0.w,acc[0][3]);
    acc[0][4]=fmaf(x0,w1.x,acc[0][4]); acc[0][5]=fmaf(x0,w1.y,acc[0][5]);
    acc[0][6]=fmaf(x0,w1.z,acc[0][6]); acc[0][7]=fmaf(x0,w1.w,acc[0][7]);
    acc[1][0]=fmaf(x1,w0.x,acc[1][0]); acc[1][1]=fmaf(x1,w0.y,acc[1][1]);
    acc[1][2]=fmaf(x1,w0.z,acc[1][2]); acc[1][3]=fmaf(x1,w0.w,acc[1][3]);
    acc[1][4]=fmaf(x1,w1.x,acc[1][4]); acc[1][5]=fmaf(x1,w1.y,acc[1][5]);
    acc[1][6]=fmaf(x1,w1.z,acc[1][6]); acc[1][7]=fmaf(x1,w1.w,acc[1][7]);
  }
  #pragma unroll
  for (int i = 0; i < 2; ++i) {
    size_t R = rowBase + rb + 32*i;
    int bI = (int)(R / (LL*NN));
    int lI = (int)((R / NN) % LL);
    int nI = (int)(R % NN);
    size_t off = ((((size_t)bI*HH + hcol)*LL + lI)*NN + nI)*DD;
    *(float4*)&O[off]     = make_float4(acc[i][0],acc[i][1],acc[i][2],acc[i][3]);
    *(float4*)&O[off + 4] = make_float4(acc[i][4],acc[i][5],acc[i][6],acc[i][7]);
  }
}

// ---------------------------------------------------------------------------
// K2: fused back-end. 384 blocks x 512 threads.
// stage K -> M (1 row/thread) -> QUARTER-SCAN rank (4 rows/thread over 1/4
// key range, partials combined) -> V staged to LDS -> vmean(wave0) ||
// attention (waves 1-7, 5 rows each, K/V from LDS) -> output.
// ---------------------------------------------------------------------------
__global__ __launch_bounds__(512) void fused_kernel(
    const float* __restrict__ Qt, const float* __restrict__ Kt,
    const float* __restrict__ Vt, const int* __restrict__ idxT,
    float* __restrict__ out) {
  const int bid = blockIdx.x;          // ((b*H + h)*L + l)
  const int l = bid % LL;
  const int h = (bid / LL) % HH;
  const int b = bid / (LL*HH);
  const int tid = threadIdx.x;
  const int wave = tid >> 6, lane = tid & 63;

  __shared__ __align__(16) float Ks[NN][PADK];        // 24KB
  __shared__ __align__(16) float Vs[NN][PADK];        // 24KB
  __shared__ __align__(16) uint64_t keys[NN];         // 4KB
  __shared__ __align__(16) int partial[NN][4];        // 8KB
  __shared__ int sel[NN];                             // 2KB
  __shared__ int topIdxL[SK + 1];
  __shared__ __align__(16) float attnOut[SK][8];
  __shared__ __align__(16) float redD[8][64][8];      // 16KB (wave-local scratch)
  __shared__ __align__(16) float vm[8];

  const size_t slabOff = (size_t)bid * (NN*DD);

  // ---- stage K rows, prefetch own q + 35 idx ----
  {
    const float4* kg = (const float4*)(Kt + slabOff);
    float4 a = kg[tid*2], c = kg[tid*2+1];
    *(float4*)&Ks[tid][0] = a; *(float4*)&Ks[tid][4] = c;
  }
  const float4* qp = (const float4*)(Qt + slabOff + (size_t)tid*DD);
  float4 qa = qp[0], qb = qp[1];
  int jv[SK];
  const int* gi = idxT + tid;
  #pragma unroll
  for (int s = 0; s < SK; ++s) jv[s] = gi[s*NN];   // coalesced, pre-barrier
  sel[tid] = -1;
  __syncthreads();

  // ---- M for own row -> key64 ----
  {
    float mx = -INFINITY, sm = 0.f;
    #pragma unroll
    for (int s = 0; s < SK; ++s) {
      int j = jv[s];
      float4 c0 = *(const float4*)&Ks[j][0];
      float4 c1 = *(const float4*)&Ks[j][4];
      float dot = qa.x*c0.x + qa.y*c0.y + qa.z*c0.z + qa.w*c0.w
                + qb.x*c1.x + qb.y*c1.y + qb.z*c1.z + qb.w*c1.w;
      mx = fmaxf(mx, dot);
      sm += dot;
    }
    float m = mx - sm * (1.0f/NN);
    uint32_t u = __float_as_uint(m);
    uint32_t fk = (u & 0x80000000u) ? ~u : (u | 0x80000000u);   // monotone map
    keys[tid] = ((uint64_t)fk << 32) | (uint32_t)(NN - 1 - tid);
  }
  __syncthreads();

  // ---- quarter-scan: thread (q = tid>>7, li = tid&127) counts keys in
  //      range [q*128, q*128+128) greater than each of rows {li, li+128,
  //      li+256, li+384}. Exact (u64 keys unique); broadcast reads. ----
  {
    const int qgrp = tid >> 7, li = tid & 127;
    uint64_t k0 = keys[li], k1 = keys[li+128], k2 = keys[li+256], k3 = keys[li+384];
    const ulonglong2* kq = (const ulonglong2*)(keys + qgrp*128);
    int c0 = 0, c1 = 0, c2 = 0, c3 = 0;
    #pragma unroll 8
    for (int jb = 0; jb < 64; ++jb) {
      ulonglong2 kv = kq[jb];            // wave-uniform broadcast read
      c0 += (kv.x > k0) ? 1 : 0; c0 += (kv.y > k0) ? 1 : 0;
      c1 += (kv.x > k1) ? 1 : 0; c1 += (kv.y > k1) ? 1 : 0;
      c2 += (kv.x > k2) ? 1 : 0; c2 += (kv.y > k2) ? 1 : 0;
      c3 += (kv.x > k3) ? 1 : 0; c3 += (kv.y > k3) ? 1 : 0;
    }
    partial[li][qgrp]     = c0;
    partial[li+128][qgrp] = c1;
    partial[li+256][qgrp] = c2;
    partial[li+384][qgrp] = c3;
  }
  // issue V load (global, coalesced) — completes during barrier/combine
  const float4* vg = (const float4*)(Vt + slabOff) + tid*2;
  float4 v0 = vg[0], v1 = vg[1];
  __syncthreads();

  // ---- combine partials -> rank; winners; stage V to LDS ----
  {
    int4 pc = *(const int4*)&partial[tid][0];
    int cnt = pc.x + pc.y + pc.z + pc.w;
    if (cnt < SK) { topIdxL[cnt] = tid; sel[tid] = cnt; }
  }
  *(float4*)&Vs[tid][0] = v0;
  *(float4*)&Vs[tid][4] = v1;
  __syncthreads();

  if (wave == 0) {
    // ---- vmean from Vs (LDS) ----
    float a[8] = {0,0,0,0,0,0,0,0};
    #pragma unroll
    for (int j = 0; j < 8; ++j) {
      int n = lane + 64*j;
      float4 w0 = *(const float4*)&Vs[n][0];
      float4 w1 = *(const float4*)&Vs[n][4];
      a[0]+=w0.x; a[1]+=w0.y; a[2]+=w0.z; a[3]+=w0.w;
      a[4]+=w1.x; a[5]+=w1.y; a[6]+=w1.z; a[7]+=w1.w;
    }
    *(float4*)&redD[0][lane][0] = make_float4(a[0],a[1],a[2],a[3]);
    *(float4*)&redD[0][lane][4] = make_float4(a[4],a[5],a[6],a[7]);
    const int d = lane & 7, g = lane >> 3;
    float s = 0.f;
    #pragma unroll
    for (int k = 0; k < 8; ++k) s += redD[0][g*8+k][d];
    s += __shfl_xor(s, 8); s += __shfl_xor(s, 16); s += __shfl_xor(s, 32);
    if (lane < 8) vm[lane] = s * (1.0f/NN);
  } else {
    // ---- attention: wave w (1..7) owns rows t = (w-1)*5 .. (w-1)*5+4 ----
    const int base = (wave - 1) * 5;
    auto do_rows = [&](int t1, int t2, bool has2) {
      const int n1 = topIdxL[t1];
      const int n2 = has2 ? topIdxL[t2] : n1;
      const float4* q1p = (const float4*)(Qt + slabOff + (size_t)n1*DD);
      const float4* q2p = (const float4*)(Qt + slabOff + (size_t)n2*DD);
      float4 q1a = q1p[0], q1b = q1p[1];     // broadcast loads
      float4 q2a = q2p[0], q2b = q2p[1];
      float p1[8], p2[8];
      float mx1 = -INFINITY, mx2 = -INFINITY;
      #pragma unroll
      for (int j = 0; j < 8; ++j) {
        int n = lane + 64*j;
        float4 ca = *(const float4*)&Ks[n][0];
        float4 cb = *(const float4*)&Ks[n][4];
        float s1 = q1a.x*ca.x + q1a.y*ca.y + q1a.z*ca.z + q1a.w*ca.w
                 + q1b.x*cb.x + q1b.y*cb.y + q1b.z*cb.z + q1b.w*cb.w;
        float s2 = q2a.x*ca.x + q2a.y*ca.y + q2a.z*ca.z + q2a.w*ca.w
                 + q2b.x*cb.x + q2b.y*cb.y + q2b.z*cb.z + q2b.w*cb.w;
        s1 *= 0.35355339059327373f;          // 1/sqrt(8)
        s2 *= 0.35355339059327373f;
        p1[j] = s1; p2[j] = s2;
        mx1 = fmaxf(mx1, s1); mx2 = fmaxf(mx2, s2);
      }
      #pragma unroll
      for (int off = 32; off >= 1; off >>= 1) {
        mx1 = fmaxf(mx1, __shfl_xor(mx1, off));
        mx2 = fmaxf(mx2, __shfl_xor(mx2, off));
      }
      float sum1 = 0.f, sum2 = 0.f;
      #pragma unroll
      for (int j = 0; j < 8; ++j) {
        p1[j] = __expf(p1[j] - mx1); sum1 += p1[j];
        p2[j] = __expf(p2[j] - mx2); sum2 += p2[j];
      }
      #pragma unroll
      for (int off = 32; off >= 1; off >>= 1) {
        sum1 += __shfl_xor(sum1, off);
        sum2 += __shfl_xor(sum2, off);
      }
      float a1[8] = {0,0,0,0,0,0,0,0}, a2[8] = {0,0,0,0,0,0,0,0};
      #pragma unroll
      for (int j = 0; j < 8; ++j) {
        int n = lane + 64*j;
        float4 va = *(const float4*)&Vs[n][0];
        float4 vb = *(const float4*)&Vs[n][4];
        float w1 = p1[j], w2 = p2[j];
        a1[0]=fmaf(w1,va.x,a1[0]); a1[1]=fmaf(w1,va.y,a1[1]);
        a1[2]=fmaf(w1,va.z,a1[2]); a1[3]=fmaf(w1,va.w,a1[3]);
        a1[4]=fmaf(w1,vb.x,a1[4]); a1[5]=fmaf(w1,vb.y,a1[5]);
        a1[6]=fmaf(w1,vb.z,a1[6]); a1[7]=fmaf(w1,vb.w,a1[7]);
        a2[0]=fmaf(w2,va.x,a2[0]); a2[1]=fmaf(w2,va.y,a2[1]);
        a2[2]=fmaf(w2,va.z,a2[2]); a2[3]=fmaf(w2,va.w,a2[3]);
        a2[4]=fmaf(w2,vb.x,a2[4]); a2[5]=fmaf(w2,vb.y,a2[5]);
        a2[6]=fmaf(w2,vb.z,a2[6]); a2[7]=fmaf(w2,vb.w,a2[7]);
      }
      const int d = lane & 7, g = lane >> 3;
      {
        *(float4*)&redD[wave][lane][0] = make_float4(a1[0],a1[1],a1[2],a1[3]);
        *(float4*)&redD[wave][lane][4] = make_float4(a1[4],a1[5],a1[6],a1[7]);
        float s = 0.f;
        #pragma unroll
        for (int k = 0; k < 8; ++k) s += redD[wave][g*8+k][d];
        s += __shfl_xor(s, 8); s += __shfl_xor(s, 16); s += __shfl_xor(s, 32);
        if (lane < 8) attnOut[t1][lane] = s * (1.0f / sum1);
      }
      if (has2) {
        *(float4*)&redD[wave][lane][0] = make_float4(a2[0],a2[1],a2[2],a2[3]);
        *(float4*)&redD[wave][lane][4] = make_float4(a2[4],a2[5],a2[6],a2[7]);
        float s = 0.f;
        #pragma unroll
        for (int k = 0; k < 8; ++k) s += redD[wave][g*8+k][d];
        s += __shfl_xor(s, 8); s += __shfl_xor(s, 16); s += __shfl_xor(s, 32);
        if (lane < 8) attnOut[t2][lane] = s * (1.0f / sum2);
      }
    };
    do_rows(base, base + 1, true);
    do_rows(base + 2, base + 3, true);
    do_rows(base + 4, base + 4, false);
  }
  __syncthreads();

  // ---- output: row n = tid ----
  {
    int t = sel[tid];
    float4 o0, o1;
    if (t >= 0) { o0 = *(const float4*)&attnOut[t][0]; o1 = *(const float4*)&attnOut[t][4]; }
    else        { o0 = *(const float4*)&vm[0];         o1 = *(const float4*)&vm[4]; }
    float* ob = out + ((size_t)(b*LL + l)*NN + tid)*DMM + h*DD;
    *(float4*)&ob[0] = o0;
    *(float4*)&ob[4] = o1;
  }
}

// ---------------------------------------------------------------------------
extern "C" void kernel_launch(void* const* d_in, const int* in_sizes, int n_in,
                              void* d_out, int out_size, void* d_ws, size_t ws_size,
                              hipStream_t stream) {
  const float* q  = (const float*)d_in[0];
  const float* k  = (const float*)d_in[1];
  const float* v  = (const float*)d_in[2];
  const float* Wq = (const float*)d_in[3];
  const float* bq = (const float*)d_in[4];
  const float* Wk = (const float*)d_in[5];
  const float* bk = (const float*)d_in[6];
  const float* Wv = (const float*)d_in[7];
  const float* bv = (const float*)d_in[8];
  float* out = (float*)d_out;

  const size_t slab = (size_t)BB*HH*LL*NN*DD;    // 1,572,864 floats
  float* qT = (float*)d_ws;
  float* kT = qT + slab;
  float* vT = kT + slab;
  int*   idxT = (int*)(vT + slab);               // 17920 ints

  proj_idx_kernel<<<dim3((BB*LL*NN)/64, 4), 256, 0, stream>>>(
      q, k, v, Wq, Wk, Wv, bq, bk, bv, qT, kT, vT, idxT);
  fused_kernel<<<BB*HH*LL, 512, 0, stream>>>(qT, kT, vT, idxT, out);
}

// Round 17
// 56.072 us; speedup vs baseline: 1.2129x; 1.0192x over previous
//
#include <hip/hip_runtime.h>
#include <stdint.h>
#include <math.h>

#define BB 4
#define LL 12
#define NN 512
#define DMM 64
#define HH 8
#define DD 8
#define SK 35
#define IDX_TOTAL (NN*SK)   // 17920
#define PADK 12             // 48B row pitch: b128-aligned, 8-bank rotation

// ---------------------------------------------------------------------------
// Threefry-2x32 (JAX-exact: 20 rounds, rotations {13,15,26,6}/{17,29,16,24})
// ---------------------------------------------------------------------------
__device__ __forceinline__ void tf2x32(uint32_t k0, uint32_t k1, uint32_t x0, uint32_t x1,
                                       uint32_t& o0, uint32_t& o1) {
  const uint32_t ks2 = k0 ^ k1 ^ 0x1BD11BDAu;
  uint32_t a = x0 + k0, b = x1 + k1;
#define TF_R(r) { a += b; b = (b << (r)) | (b >> (32 - (r))); b ^= a; }
  TF_R(13) TF_R(15) TF_R(26) TF_R(6)
  a += k1;  b += ks2 + 1u;
  TF_R(17) TF_R(29) TF_R(16) TF_R(24)
  a += ks2; b += k0 + 2u;
  TF_R(13) TF_R(15) TF_R(26) TF_R(6)
  a += k0;  b += k1 + 3u;
  TF_R(17) TF_R(29) TF_R(16) TF_R(24)
  a += k1;  b += ks2 + 4u;
  TF_R(13) TF_R(15) TF_R(26) TF_R(6)
  a += ks2; b += k0 + 5u;
#undef TF_R
  o0 = a; o1 = b;
}

// ---------------------------------------------------------------------------
// K1: fused projections (y=0,1,2; 64-row tiles) + idx generation (y=3).
// ---------------------------------------------------------------------------
__global__ __launch_bounds__(256) void proj_idx_kernel(
    const float* __restrict__ Xq, const float* __restrict__ Xk, const float* __restrict__ Xv,
    const float* __restrict__ Wq_, const float* __restrict__ Wk_, const float* __restrict__ Wv_,
    const float* __restrict__ bq_, const float* __restrict__ bk_, const float* __restrict__ bv_,
    float* __restrict__ Oq, float* __restrict__ Ok, float* __restrict__ Ov,
    int* __restrict__ idxT) {
  const int tz = blockIdx.y;
  if (tz == 3) {
    int gid = blockIdx.x * 256 + threadIdx.x;
    if (gid < IDX_TOTAL) {
      int r = gid & (NN - 1);     // idxT flat = s*512 + r
      int s = gid >> 9;
      uint32_t ka, kb;
      tf2x32(0u, 42u, 0u, 1u, ka, kb);
      uint32_t b1, b2;
      tf2x32(ka, kb, 0u, (uint32_t)(r * SK + s), b1, b2);   // counter = row-major (r,s)
      idxT[gid] = (int)((b1 ^ b2) & (uint32_t)(NN - 1));
    }
    return;
  }
  const float* X    = (tz == 0) ? Xq  : (tz == 1) ? Xk  : Xv;
  const float* W    = (tz == 0) ? Wq_ : (tz == 1) ? Wk_ : Wv_;
  const float* bias = (tz == 0) ? bq_ : (tz == 1) ? bk_ : bv_;
  float* O          = (tz == 0) ? Oq  : (tz == 1) ? Ok  : Ov;

  __shared__ __align__(16) float Ws[64][64];
  __shared__ __align__(16) float Xs[64][68];
  __shared__ float bs[64];

  const int tid = threadIdx.x;
  const size_t rowBase = (size_t)blockIdx.x * 64;
  const float* Xb = X + rowBase * 64;
  #pragma unroll
  for (int i = 0; i < 4; ++i) {
    int idx = tid + i*256;
    ((float4*)Ws)[idx] = ((const float4*)W)[idx];
    int r = idx >> 4, c = (idx & 15) << 2;
    *(float4*)&Xs[r][c] = ((const float4*)Xb)[idx];
  }
  if (tid < 64) bs[tid] = bias[tid];
  __syncthreads();

  const int hcol = tid & 7;   // head (8 cols)
  const int rb   = tid >> 3;  // 0..31; rows rb, rb+32
  float4 bv0 = *(float4*)&bs[hcol*8];
  float4 bv1 = *(float4*)&bs[hcol*8+4];
  float acc[2][8];
  #pragma unroll
  for (int i = 0; i < 2; ++i) {
    acc[i][0]=bv0.x; acc[i][1]=bv0.y; acc[i][2]=bv0.z; acc[i][3]=bv0.w;
    acc[i][4]=bv1.x; acc[i][5]=bv1.y; acc[i][6]=bv1.z; acc[i][7]=bv1.w;
  }
  #pragma unroll 8
  for (int m = 0; m < 64; ++m) {
    float4 w0 = *(const float4*)&Ws[m][hcol*8];
    float4 w1 = *(const float4*)&Ws[m][hcol*8+4];
    float x0 = Xs[rb][m];
    float x1 = Xs[rb+32][m];
    acc[0][0]=fmaf(x0,w0.x,acc[0][0]); acc[0][1]=fmaf(x0,w0.y,acc[0][1]);
    acc[0][2]=fmaf(x0,w0.z,acc[0][2]); acc[0][3]=fmaf(x0,w0.w,acc[0][3]);
    acc[0][4]=fmaf(x0,w1.x,acc[0][4]); acc[0][5]=fmaf(x0,w1.y,acc[0][5]);
    acc[0][6]=fmaf(x0,w1.z,acc[0][6]); acc[0][7]=fmaf(x0,w1.w,acc[0][7]);
    acc[1][0]=fmaf(x1,w0.x,acc[1][0]); acc[1][1]=fmaf(x1,w0.y,acc[1][1]);
    acc[1][2]=fmaf(x1,w0.z,acc[1][2]); acc[1][3]=fmaf(x1,w0.w,acc[1][3]);
    acc[1][4]=fmaf(x1,w1.x,acc[1][4]); acc[1][5]=fmaf(x1,w1.y,acc[1][5]);
    acc[1][6]=fmaf(x1,w1.z,acc[1][6]); acc[1][7]=fmaf(x1,w1.w,acc[1][7]);
  }
  #pragma unroll
  for (int i = 0; i < 2; ++i) {
    size_t R = rowBase + rb + 32*i;
    int bI = (int)(R / (LL*NN));
    int lI = (int)((R / NN) % LL);
    int nI = (int)(R % NN);
    size_t off = ((((size_t)bI*HH + hcol)*LL + lI)*NN + nI)*DD;
    *(float4*)&O[off]     = make_float4(acc[i][0],acc[i][1],acc[i][2],acc[i][3]);
    *(float4*)&O[off + 4] = make_float4(acc[i][4],acc[i][5],acc[i][6],acc[i][7]);
  }
}

// ---------------------------------------------------------------------------
// K2: fused back-end. 384 blocks x 512 threads, ~73KB LDS (2 blocks/CU).
// stage K -> M (1 row/thread) -> QUARTER-SCAN rank (partials aliased into
// redD's storage) -> V staged to LDS -> vmean(wave0) || attention
// (waves 1-7, 5 rows each, K/V from LDS) -> output.
// ---------------------------------------------------------------------------
__global__ __launch_bounds__(512) void fused_kernel(
    const float* __restrict__ Qt, const float* __restrict__ Kt,
    const float* __restrict__ Vt, const int* __restrict__ idxT,
    float* __restrict__ out) {
  const int bid = blockIdx.x;          // ((b*H + h)*L + l)
  const int l = bid % LL;
  const int h = (bid / LL) % HH;
  const int b = bid / (LL*HH);
  const int tid = threadIdx.x;
  const int wave = tid >> 6, lane = tid & 63;

  __shared__ __align__(16) float Ks[NN][PADK];        // 24KB
  __shared__ __align__(16) float Vs[NN][PADK];        // 24KB
  __shared__ __align__(16) uint64_t keys[NN];         // 4KB
  __shared__ int sel[NN];                             // 2KB
  __shared__ int topIdxL[SK + 1];
  __shared__ __align__(16) float attnOut[SK][8];
  __shared__ __align__(16) float redD[8][64][8];      // 16KB; scan partials alias here
  __shared__ __align__(16) float vm[8];

  int (*partial)[4] = (int(*)[4])redD;                // 8KB alias (temporally disjoint)

  const size_t slabOff = (size_t)bid * (NN*DD);

  // ---- stage K rows, prefetch own q + 35 idx ----
  {
    const float4* kg = (const float4*)(Kt + slabOff);
    float4 a = kg[tid*2], c = kg[tid*2+1];
    *(float4*)&Ks[tid][0] = a; *(float4*)&Ks[tid][4] = c;
  }
  const float4* qp = (const float4*)(Qt + slabOff + (size_t)tid*DD);
  float4 qa = qp[0], qb = qp[1];
  int jv[SK];
  const int* gi = idxT + tid;
  #pragma unroll
  for (int s = 0; s < SK; ++s) jv[s] = gi[s*NN];   // coalesced, pre-barrier
  sel[tid] = -1;
  __syncthreads();

  // ---- M for own row -> key64 ----
  {
    float mx = -INFINITY, sm = 0.f;
    #pragma unroll
    for (int s = 0; s < SK; ++s) {
      int j = jv[s];
      float4 c0 = *(const float4*)&Ks[j][0];
      float4 c1 = *(const float4*)&Ks[j][4];
      float dot = qa.x*c0.x + qa.y*c0.y + qa.z*c0.z + qa.w*c0.w
                + qb.x*c1.x + qb.y*c1.y + qb.z*c1.z + qb.w*c1.w;
      mx = fmaxf(mx, dot);
      sm += dot;
    }
    float m = mx - sm * (1.0f/NN);
    uint32_t u = __float_as_uint(m);
    uint32_t fk = (u & 0x80000000u) ? ~u : (u | 0x80000000u);   // monotone map
    keys[tid] = ((uint64_t)fk << 32) | (uint32_t)(NN - 1 - tid);
  }
  __syncthreads();

  // ---- quarter-scan: thread (q = tid>>7, li = tid&127) counts keys in
  //      range [q*128, q*128+128) greater than each of rows {li, li+128,
  //      li+256, li+384}. Exact (u64 keys unique); broadcast reads. ----
  {
    const int qgrp = tid >> 7, li = tid & 127;
    uint64_t k0 = keys[li], k1 = keys[li+128], k2 = keys[li+256], k3 = keys[li+384];
    const ulonglong2* kq = (const ulonglong2*)(keys + qgrp*128);
    int c0 = 0, c1 = 0, c2 = 0, c3 = 0;
    #pragma unroll 8
    for (int jb = 0; jb < 64; ++jb) {
      ulonglong2 kv = kq[jb];            // wave-uniform broadcast read
      c0 += (kv.x > k0) ? 1 : 0; c0 += (kv.y > k0) ? 1 : 0;
      c1 += (kv.x > k1) ? 1 : 0; c1 += (kv.y > k1) ? 1 : 0;
      c2 += (kv.x > k2) ? 1 : 0; c2 += (kv.y > k2) ? 1 : 0;
      c3 += (kv.x > k3) ? 1 : 0; c3 += (kv.y > k3) ? 1 : 0;
    }
    partial[li][qgrp]     = c0;
    partial[li+128][qgrp] = c1;
    partial[li+256][qgrp] = c2;
    partial[li+384][qgrp] = c3;
  }
  // issue V load (global, coalesced) — completes during barrier/combine
  const float4* vg = (const float4*)(Vt + slabOff) + tid*2;
  float4 v0 = vg[0], v1 = vg[1];
  __syncthreads();

  // ---- combine partials -> rank; winners; stage V to LDS ----
  {
    int4 pc = *(const int4*)&partial[tid][0];
    int cnt = pc.x + pc.y + pc.z + pc.w;
    if (cnt < SK) { topIdxL[cnt] = tid; sel[tid] = cnt; }
  }
  __syncthreads();                      // partial reads done before redD reuse
  *(float4*)&Vs[tid][0] = v0;
  *(float4*)&Vs[tid][4] = v1;
  __syncthreads();

  if (wave == 0) {
    // ---- vmean from Vs (LDS) ----
    float a[8] = {0,0,0,0,0,0,0,0};
    #pragma unroll
    for (int j = 0; j < 8; ++j) {
      int n = lane + 64*j;
      float4 w0 = *(const float4*)&Vs[n][0];
      float4 w1 = *(const float4*)&Vs[n][4];
      a[0]+=w0.x; a[1]+=w0.y; a[2]+=w0.z; a[3]+=w0.w;
      a[4]+=w1.x; a[5]+=w1.y; a[6]+=w1.z; a[7]+=w1.w;
    }
    *(float4*)&redD[0][lane][0] = make_float4(a[0],a[1],a[2],a[3]);
    *(float4*)&redD[0][lane][4] = make_float4(a[4],a[5],a[6],a[7]);
    const int d = lane & 7, g = lane >> 3;
    float s = 0.f;
    #pragma unroll
    for (int k = 0; k < 8; ++k) s += redD[0][g*8+k][d];
    s += __shfl_xor(s, 8); s += __shfl_xor(s, 16); s += __shfl_xor(s, 32);
    if (lane < 8) vm[lane] = s * (1.0f/NN);
  } else {
    // ---- attention: wave w (1..7) owns rows t = (w-1)*5 .. (w-1)*5+4 ----
    const int base = (wave - 1) * 5;
    auto do_rows = [&](int t1, int t2, bool has2) {
      const int n1 = topIdxL[t1];
      const int n2 = has2 ? topIdxL[t2] : n1;
      const float4* q1p = (const float4*)(Qt + slabOff + (size_t)n1*DD);
      const float4* q2p = (const float4*)(Qt + slabOff + (size_t)n2*DD);
      float4 q1a = q1p[0], q1b = q1p[1];     // broadcast loads
      float4 q2a = q2p[0], q2b = q2p[1];
      float p1[8], p2[8];
      float mx1 = -INFINITY, mx2 = -INFINITY;
      #pragma unroll
      for (int j = 0; j < 8; ++j) {
        int n = lane + 64*j;
        float4 ca = *(const float4*)&Ks[n][0];
        float4 cb = *(const float4*)&Ks[n][4];
        float s1 = q1a.x*ca.x + q1a.y*ca.y + q1a.z*ca.z + q1a.w*ca.w
                 + q1b.x*cb.x + q1b.y*cb.y + q1b.z*cb.z + q1b.w*cb.w;
        float s2 = q2a.x*ca.x + q2a.y*ca.y + q2a.z*ca.z + q2a.w*ca.w
                 + q2b.x*cb.x + q2b.y*cb.y + q2b.z*cb.z + q2b.w*cb.w;
        s1 *= 0.35355339059327373f;          // 1/sqrt(8)
        s2 *= 0.35355339059327373f;
        p1[j] = s1; p2[j] = s2;
        mx1 = fmaxf(mx1, s1); mx2 = fmaxf(mx2, s2);
      }
      #pragma unroll
      for (int off = 32; off >= 1; off >>= 1) {
        mx1 = fmaxf(mx1, __shfl_xor(mx1, off));
        mx2 = fmaxf(mx2, __shfl_xor(mx2, off));
      }
      float sum1 = 0.f, sum2 = 0.f;
      #pragma unroll
      for (int j = 0; j < 8; ++j) {
        p1[j] = __expf(p1[j] - mx1); sum1 += p1[j];
        p2[j] = __expf(p2[j] - mx2); sum2 += p2[j];
      }
      #pragma unroll
      for (int off = 32; off >= 1; off >>= 1) {
        sum1 += __shfl_xor(sum1, off);
        sum2 += __shfl_xor(sum2, off);
      }
      float a1[8] = {0,0,0,0,0,0,0,0}, a2[8] = {0,0,0,0,0,0,0,0};
      #pragma unroll
      for (int j = 0; j < 8; ++j) {
        int n = lane + 64*j;
        float4 va = *(const float4*)&Vs[n][0];
        float4 vb = *(const float4*)&Vs[n][4];
        float w1 = p1[j], w2 = p2[j];
        a1[0]=fmaf(w1,va.x,a1[0]); a1[1]=fmaf(w1,va.y,a1[1]);
        a1[2]=fmaf(w1,va.z,a1[2]); a1[3]=fmaf(w1,va.w,a1[3]);
        a1[4]=fmaf(w1,vb.x,a1[4]); a1[5]=fmaf(w1,vb.y,a1[5]);
        a1[6]=fmaf(w1,vb.z,a1[6]); a1[7]=fmaf(w1,vb.w,a1[7]);
        a2[0]=fmaf(w2,va.x,a2[0]); a2[1]=fmaf(w2,va.y,a2[1]);
        a2[2]=fmaf(w2,va.z,a2[2]); a2[3]=fmaf(w2,va.w,a2[3]);
        a2[4]=fmaf(w2,vb.x,a2[4]); a2[5]=fmaf(w2,vb.y,a2[5]);
        a2[6]=fmaf(w2,vb.z,a2[6]); a2[7]=fmaf(w2,vb.w,a2[7]);
      }
      const int d = lane & 7, g = lane >> 3;
      {
        *(float4*)&redD[wave][lane][0] = make_float4(a1[0],a1[1],a1[2],a1[3]);
        *(float4*)&redD[wave][lane][4] = make_float4(a1[4],a1[5],a1[6],a1[7]);
        float s = 0.f;
        #pragma unroll
        for (int k = 0; k < 8; ++k) s += redD[wave][g*8+k][d];
        s += __shfl_xor(s, 8); s += __shfl_xor(s, 16); s += __shfl_xor(s, 32);
        if (lane < 8) attnOut[t1][lane] = s * (1.0f / sum1);
      }
      if (has2) {
        *(float4*)&redD[wave][lane][0] = make_float4(a2[0],a2[1],a2[2],a2[3]);
        *(float4*)&redD[wave][lane][4] = make_float4(a2[4],a2[5],a2[6],a2[7]);
        float s = 0.f;
        #pragma unroll
        for (int k = 0; k < 8; ++k) s += redD[wave][g*8+k][d];
        s += __shfl_xor(s, 8); s += __shfl_xor(s, 16); s += __shfl_xor(s, 32);
        if (lane < 8) attnOut[t2][lane] = s * (1.0f / sum2);
      }
    };
    do_rows(base, base + 1, true);
    do_rows(base + 2, base + 3, true);
    do_rows(base + 4, base + 4, false);
  }
  __syncthreads();

  // ---- output: row n = tid ----
  {
    int t = sel[tid];
    float4 o0, o1;
    if (t >= 0) { o0 = *(const float4*)&attnOut[t][0]; o1 = *(const float4*)&attnOut[t][4]; }
    else        { o0 = *(const float4*)&vm[0];         o1 = *(const float4*)&vm[4]; }
    float* ob = out + ((size_t)(b*LL + l)*NN + tid)*DMM + h*DD;
    *(float4*)&ob[0] = o0;
    *(float4*)&ob[4] = o1;
  }
}

// ---------------------------------------------------------------------------
extern "C" void kernel_launch(void* const* d_in, const int* in_sizes, int n_in,
                              void* d_out, int out_size, void* d_ws, size_t ws_size,
                              hipStream_t stream) {
  const float* q  = (const float*)d_in[0];
  const float* k  = (const float*)d_in[1];
  const float* v  = (const float*)d_in[2];
  const float* Wq = (const float*)d_in[3];
  const float* bq = (const float*)d_in[4];
  const float* Wk = (const float*)d_in[5];
  const float* bk = (const float*)d_in[6];
  const float* Wv = (const float*)d_in[7];
  const float* bv = (const float*)d_in[8];
  float* out = (float*)d_out;

  const size_t slab = (size_t)BB*HH*LL*NN*DD;    // 1,572,864 floats
  float* qT = (float*)d_ws;
  float* kT = qT + slab;
  float* vT = kT + slab;
  int*   idxT = (int*)(vT + slab);               // 17920 ints

  proj_idx_kernel<<<dim3((BB*LL*NN)/64, 4), 256, 0, stream>>>(
      q, k, v, Wq, Wk, Wv, bq, bk, bv, qT, kT, vT, idxT);
  fused_kernel<<<BB*HH*LL, 512, 0, stream>>>(qT, kT, vT, idxT, out);
}